// Round 1
// baseline (9478.308 us; speedup 1.0000x reference)
//
#include <hip/hip_runtime.h>
#include <hip/hip_bf16.h>
#include <math.h>

#define B_ 128
#define S_ 128
#define D_ 1024
#define DS_ 64
#define E3_ 3072   // 3*D

// ---------------------------------------------------------------------------
// Tiled f32 GEMM:  C[M,N] = act( A[M,K] @ W[N,K]^T + bias[N] )
// A may be a logical concat of two row-major matrices split at column ksplit
// (A0 has row stride ksplit, A1 has row stride K-ksplit). Pass A1=nullptr and
// ksplit=K for a single matrix.
// Tiles: BM=BN=64, BK=16, 256 threads, 4x4 outputs/thread.
// Requires M%64==0, N%64==0, K%16==0 (true for all uses here).
// ---------------------------------------------------------------------------
template <int ACT> // 0 = none, 1 = exact gelu
__global__ __launch_bounds__(256) void gemm_nt(
    const float* __restrict__ A0, const float* __restrict__ A1, int ksplit,
    const float* __restrict__ W, const float* __restrict__ bias,
    float* __restrict__ C, int M, int N, int K)
{
    __shared__ float As[16][68];  // [k][m], pad 68 keeps 16B align + spreads banks
    __shared__ float Bs[16][68];  // [k][n]

    const int n0 = blockIdx.x * 64;
    const int m0 = blockIdx.y * 64;
    const int tid = threadIdx.x;
    const int tx = tid & 15;      // n direction (x4)
    const int ty = tid >> 4;      // m direction (x4)

    // loader mapping: each thread loads one float4 of A-tile and one of W-tile
    const int lm = tid >> 2;        // 0..63 (row within tile)
    const int lk = (tid & 3) * 4;   // 0,4,8,12 (col within tile)

    const int s1 = ksplit;          // A0 row stride
    const int s2 = K - ksplit;      // A1 row stride

    float acc[4][4] = {};

    for (int k0 = 0; k0 < K; k0 += 16) {
        // --- global -> LDS ---
        const int arow = m0 + lm;
        const int acol = k0 + lk;
        float4 av;
        if (acol < s1) {
            av = *(const float4*)(A0 + (size_t)arow * s1 + acol);
        } else {
            av = *(const float4*)(A1 + (size_t)arow * s2 + (acol - s1));
        }
        const float4 wv = *(const float4*)(W + (size_t)(n0 + lm) * K + acol);

        As[lk + 0][lm] = av.x; As[lk + 1][lm] = av.y;
        As[lk + 2][lm] = av.z; As[lk + 3][lm] = av.w;
        Bs[lk + 0][lm] = wv.x; Bs[lk + 1][lm] = wv.y;
        Bs[lk + 2][lm] = wv.z; Bs[lk + 3][lm] = wv.w;
        __syncthreads();

        // --- FMA inner loop ---
        #pragma unroll
        for (int kk = 0; kk < 16; kk++) {
            const float4 a4 = *(const float4*)&As[kk][ty * 4];
            const float4 b4 = *(const float4*)&Bs[kk][tx * 4];
            const float ar[4] = {a4.x, a4.y, a4.z, a4.w};
            const float br[4] = {b4.x, b4.y, b4.z, b4.w};
            #pragma unroll
            for (int i = 0; i < 4; i++)
                #pragma unroll
                for (int j = 0; j < 4; j++)
                    acc[i][j] = fmaf(ar[i], br[j], acc[i][j]);
        }
        __syncthreads();
    }

    // --- epilogue ---
    #pragma unroll
    for (int i = 0; i < 4; i++) {
        const int r = m0 + ty * 4 + i;
        #pragma unroll
        for (int j = 0; j < 4; j++) {
            const int c = n0 + tx * 4 + j;
            float v = acc[i][j] + bias[c];
            if (ACT == 1) v = 0.5f * v * (1.0f + erff(v * 0.7071067811865475f));
            C[(size_t)r * N + c] = v;
        }
    }
}

// ---------------------------------------------------------------------------
// GRU recurrent matvec (one step i):
//   gh[b, e] = sum_k h[b, fa[b,i], k] * Wh[e, k] + bh[e]     (b<128, e<3072)
// For i==0 the gathered state is all zeros -> gh = bh.
// Tiles: BM=32 (b), BN=64 (e), BK=16; grid (48, 4), 256 threads.
// ---------------------------------------------------------------------------
__global__ __launch_bounds__(256) void gru_matvec(
    const float* __restrict__ h, const float* __restrict__ Wh,
    const float* __restrict__ bh, const int* __restrict__ fa,
    float* __restrict__ gh, int i)
{
    __shared__ float As[16][33];  // [k][b-local]
    __shared__ float Bs[16][68];  // [k][e-local]

    const int n0 = blockIdx.x * 64;
    const int m0 = blockIdx.y * 32;
    const int tid = threadIdx.x;
    const int tx = tid & 15;   // e direction (x4)
    const int ty = tid >> 4;   // b direction: rows ty and ty+16

    // A loader: 32x16 tile, float2 per thread
    const int lmA = tid >> 3;        // 0..31
    const int lkA = (tid & 7) * 2;   // 0,2,..,14
    const int bA = m0 + lmA;
    const float* hxp = nullptr;
    if (i > 0) {
        const int pi = fa[bA * S_ + i];
        hxp = h + ((size_t)(bA * S_ + pi)) * D_;
    }
    // W loader: 64x16 tile, float4 per thread
    const int lnW = tid >> 2;        // 0..63
    const int lkW = (tid & 3) * 4;
    const float* wp = Wh + (size_t)(n0 + lnW) * D_;

    float acc[2][4] = {};

    for (int k0 = 0; k0 < D_; k0 += 16) {
        float2 av = make_float2(0.f, 0.f);
        if (i > 0) av = *(const float2*)(hxp + k0 + lkA);
        const float4 wv = *(const float4*)(wp + k0 + lkW);

        As[lkA + 0][lmA] = av.x;
        As[lkA + 1][lmA] = av.y;
        Bs[lkW + 0][lnW] = wv.x; Bs[lkW + 1][lnW] = wv.y;
        Bs[lkW + 2][lnW] = wv.z; Bs[lkW + 3][lnW] = wv.w;
        __syncthreads();

        #pragma unroll
        for (int kk = 0; kk < 16; kk++) {
            const float a0 = As[kk][ty];
            const float a1 = As[kk][ty + 16];
            const float4 b4 = *(const float4*)&Bs[kk][tx * 4];
            const float br[4] = {b4.x, b4.y, b4.z, b4.w};
            #pragma unroll
            for (int j = 0; j < 4; j++) {
                acc[0][j] = fmaf(a0, br[j], acc[0][j]);
                acc[1][j] = fmaf(a1, br[j], acc[1][j]);
            }
        }
        __syncthreads();
    }

    #pragma unroll
    for (int mi = 0; mi < 2; mi++) {
        const int bb = m0 + ty + mi * 16;
        #pragma unroll
        for (int j = 0; j < 4; j++) {
            const int e = n0 + tx * 4 + j;
            gh[(size_t)bb * E3_ + e] = acc[mi][j] + bh[e];
        }
    }
}

// ---------------------------------------------------------------------------
// block-wide reduction of two values over 256 threads (4 waves of 64)
// ---------------------------------------------------------------------------
__device__ inline float2 blockReduce2(float s1, float s2, float* sm)
{
    #pragma unroll
    for (int off = 32; off > 0; off >>= 1) {
        s1 += __shfl_down(s1, off);
        s2 += __shfl_down(s2, off);
    }
    const int lane = threadIdx.x & 63;
    const int w = threadIdx.x >> 6;
    if (lane == 0) { sm[w] = s1; sm[w + 4] = s2; }
    __syncthreads();
    const float r1 = sm[0] + sm[1] + sm[2] + sm[3];
    const float r2 = sm[4] + sm[5] + sm[6] + sm[7];
    __syncthreads();
    return make_float2(r1, r2);
}

__device__ inline float sigmoidf_(float x) { return 1.0f / (1.0f + expf(-x)); }

// ---------------------------------------------------------------------------
// GRU gates (one step i): per block b, 256 threads x 4 contiguous d each.
//   r = sigmoid(LN(xr+hr; g0,b0)); z = sigmoid(LN(xz+hz; g1,b1));
//   n = tanh(LN(xn + r*hn; g2,b2)); h[b,i] = (1-z)*n + z*hx
// ---------------------------------------------------------------------------
__global__ __launch_bounds__(256) void gru_gates(
    const float* __restrict__ gx_all, const float* __restrict__ gh_all,
    const float* __restrict__ ln_g, const float* __restrict__ ln_b,
    const int* __restrict__ fa, float* __restrict__ h, int i)
{
    __shared__ float sm[8];
    const int b = blockIdx.x;
    const int tid = threadIdx.x;
    const int d0 = tid * 4;

    const float* gx = gx_all + (size_t)(b * S_ + i) * E3_;
    const float* gh = gh_all + (size_t)b * E3_;
    float* hout = h + (size_t)(b * S_ + i) * D_;

    float hx[4] = {0.f, 0.f, 0.f, 0.f};
    if (i > 0) {
        const int pi = fa[b * S_ + i];
        const float4 v = *(const float4*)(h + (size_t)(b * S_ + pi) * D_ + d0);
        hx[0] = v.x; hx[1] = v.y; hx[2] = v.z; hx[3] = v.w;
    }

    // ---- gate r ----
    float u[4];
    {
        const float4 a = *(const float4*)(gx + d0);
        const float4 c = *(const float4*)(gh + d0);
        u[0] = a.x + c.x; u[1] = a.y + c.y; u[2] = a.z + c.z; u[3] = a.w + c.w;
    }
    float r[4];
    {
        float p1 = u[0] + u[1] + u[2] + u[3];
        float p2 = u[0]*u[0] + u[1]*u[1] + u[2]*u[2] + u[3]*u[3];
        const float2 t = blockReduce2(p1, p2, sm);
        const float mean = t.x * (1.0f / 1024.0f);
        const float var = t.y * (1.0f / 1024.0f) - mean * mean;
        const float rstd = rsqrtf(var + 1e-5f);
        const float4 g = *(const float4*)(ln_g + d0);
        const float4 be = *(const float4*)(ln_b + d0);
        const float gr[4] = {g.x, g.y, g.z, g.w};
        const float br[4] = {be.x, be.y, be.z, be.w};
        #pragma unroll
        for (int j = 0; j < 4; j++)
            r[j] = sigmoidf_((u[j] - mean) * rstd * gr[j] + br[j]);
    }

    // ---- gate z ----
    {
        const float4 a = *(const float4*)(gx + D_ + d0);
        const float4 c = *(const float4*)(gh + D_ + d0);
        u[0] = a.x + c.x; u[1] = a.y + c.y; u[2] = a.z + c.z; u[3] = a.w + c.w;
    }
    float z[4];
    {
        float p1 = u[0] + u[1] + u[2] + u[3];
        float p2 = u[0]*u[0] + u[1]*u[1] + u[2]*u[2] + u[3]*u[3];
        const float2 t = blockReduce2(p1, p2, sm);
        const float mean = t.x * (1.0f / 1024.0f);
        const float var = t.y * (1.0f / 1024.0f) - mean * mean;
        const float rstd = rsqrtf(var + 1e-5f);
        const float4 g = *(const float4*)(ln_g + D_ + d0);
        const float4 be = *(const float4*)(ln_b + D_ + d0);
        const float gr[4] = {g.x, g.y, g.z, g.w};
        const float br[4] = {be.x, be.y, be.z, be.w};
        #pragma unroll
        for (int j = 0; j < 4; j++)
            z[j] = sigmoidf_((u[j] - mean) * rstd * gr[j] + br[j]);
    }

    // ---- gate n ----
    {
        const float4 a = *(const float4*)(gx + 2 * D_ + d0);
        const float4 c = *(const float4*)(gh + 2 * D_ + d0);
        u[0] = a.x + r[0] * c.x; u[1] = a.y + r[1] * c.y;
        u[2] = a.z + r[2] * c.z; u[3] = a.w + r[3] * c.w;
    }
    float hn[4];
    {
        float p1 = u[0] + u[1] + u[2] + u[3];
        float p2 = u[0]*u[0] + u[1]*u[1] + u[2]*u[2] + u[3]*u[3];
        const float2 t = blockReduce2(p1, p2, sm);
        const float mean = t.x * (1.0f / 1024.0f);
        const float var = t.y * (1.0f / 1024.0f) - mean * mean;
        const float rstd = rsqrtf(var + 1e-5f);
        const float4 g = *(const float4*)(ln_g + 2 * D_ + d0);
        const float4 be = *(const float4*)(ln_b + 2 * D_ + d0);
        const float gr[4] = {g.x, g.y, g.z, g.w};
        const float br[4] = {be.x, be.y, be.z, be.w};
        #pragma unroll
        for (int j = 0; j < 4; j++) {
            const float n = tanhf((u[j] - mean) * rstd * gr[j] + br[j]);
            hn[j] = (1.0f - z[j]) * n + z[j] * hx[j];
        }
    }

    float4 o;
    o.x = hn[0]; o.y = hn[1]; o.z = hn[2]; o.w = hn[3];
    *(float4*)(hout + d0) = o;
}

// ---------------------------------------------------------------------------
// emb scan, parallelized via ancestor chains:
//   emb[b,i, j*64+t] = shorted[b, fa^j(i), t] unless the chain passed through
//   index 0 before hop j (then 0).  One block per (b,i).
// ---------------------------------------------------------------------------
__global__ __launch_bounds__(256) void emb_fill(
    const float* __restrict__ shorted, const int* __restrict__ fa,
    float* __restrict__ emb)
{
    __shared__ int src[16];
    const int bi = blockIdx.x;       // b*128 + i
    const int b = bi >> 7;
    const int i = bi & 127;
    if (threadIdx.x == 0) {
        int cur = i;
        bool dead = false;
        #pragma unroll
        for (int j = 0; j < 16; j++) {
            src[j] = dead ? -1 : cur;
            if (cur == 0) dead = true;
            cur = fa[(b << 7) + cur];
        }
    }
    __syncthreads();
    const int d = threadIdx.x * 4;
    const int j = d >> 6;
    const int s = src[j];
    float4 v = make_float4(0.f, 0.f, 0.f, 0.f);
    if (s >= 0)
        v = *(const float4*)(shorted + ((size_t)(b * S_ + s)) * DS_ + (d & 63));
    *(float4*)(emb + (size_t)bi * D_ + d) = v;
}

// ---------------------------------------------------------------------------
extern "C" void kernel_launch(void* const* d_in, const int* in_sizes, int n_in,
                              void* d_out, int out_size, void* d_ws, size_t ws_size,
                              hipStream_t stream)
{
    const float* token = (const float*)d_in[0];
    const float* Wx    = (const float*)d_in[1];
    const float* bx    = (const float*)d_in[2];
    const float* Wh    = (const float*)d_in[3];
    const float* bh    = (const float*)d_in[4];
    const float* ln_g  = (const float*)d_in[5];
    const float* ln_b  = (const float*)d_in[6];
    const float* fc0_w = (const float*)d_in[7];
    const float* fc0_b = (const float*)d_in[8];
    const float* fc1_w = (const float*)d_in[9];
    const float* fc1_b = (const float*)d_in[10];
    const float* cmb_w = (const float*)d_in[11];
    const float* cmb_b = (const float*)d_in[12];
    const int*   fa    = (const int*)d_in[13];

    float* out = (float*)d_out;
    char* ws = (char*)d_ws;

    const int M = B_ * S_;                       // 16384
    // workspace layout (bytes)
    const size_t gx_bytes = (size_t)M * E3_ * 4; // 201,326,592
    const size_t gh_bytes = (size_t)B_ * E3_ * 4;
    float* gx      = (float*)ws;                           // [M,3072]
    float* gh      = (float*)(ws + gx_bytes);              // [128,3072]
    float* shorted = (float*)(ws + gx_bytes + gh_bytes);   // [M,64]
    // after scan, gx region is dead -> reuse for h0 and emb
    float* h0  = (float*)ws;                               // [M,1024]
    float* emb = (float*)(ws + (size_t)M * D_ * 4);        // [M,1024]
    float* h = out;  // gru_emb lives in d_out during scan; out fully rewritten at end

    // 1. gx = token @ Wx^T + bx
    gemm_nt<0><<<dim3(E3_ / 64, M / 64), 256, 0, stream>>>(
        token, nullptr, D_, Wx, bx, gx, M, E3_, D_);

    // 2. GRU scan (sequential over S)
    for (int i = 0; i < S_; i++) {
        gru_matvec<<<dim3(E3_ / 64, B_ / 32), 256, 0, stream>>>(h, Wh, bh, fa, gh, i);
        gru_gates<<<B_, 256, 0, stream>>>(gx, gh, ln_g, ln_b, fa, h, i);
    }

    // 3. h0 = gelu(h @ fc0_w^T + fc0_b)
    gemm_nt<1><<<dim3(D_ / 64, M / 64), 256, 0, stream>>>(
        h, nullptr, D_, fc0_w, fc0_b, h0, M, D_, D_);

    // 4. shorted = h0 @ fc1_w^T + fc1_b
    gemm_nt<0><<<dim3(DS_ / 64, M / 64), 256, 0, stream>>>(
        h0, nullptr, D_, fc1_w, fc1_b, shorted, M, DS_, D_);

    // 5. emb via parallel ancestor-chain gather
    emb_fill<<<M, 256, 0, stream>>>(shorted, fa, emb);

    // 6. out = [token, emb] @ cmb_w^T + cmb_b
    gemm_nt<0><<<dim3(D_ / 64, M / 64), 256, 0, stream>>>(
        token, emb, D_, cmb_w, cmb_b, out, M, D_, 2 * D_);
}

// Round 2
// 6951.486 us; speedup vs baseline: 1.3635x; 1.3635x over previous
//
#include <hip/hip_runtime.h>
#include <hip/hip_bf16.h>
#include <math.h>

#define B_ 128
#define S_ 128
#define D_ 1024
#define DS_ 64
#define E3_ 3072   // 3*D

typedef short s16x8 __attribute__((ext_vector_type(8)));
typedef float f32x4 __attribute__((ext_vector_type(4)));

__device__ __forceinline__ void async_copy16(const void* g, void* l) {
    __builtin_amdgcn_global_load_lds(
        (const __attribute__((address_space(1))) void*)g,
        (__attribute__((address_space(3))) void*)l, 16, 0, 0);
}

// ---------------------------------------------------------------------------
// bf16 MFMA GEMM (m97 structure): C[M,N] = act( A[M,K] @ W[N,K]^T + bias[N] )
// A is bf16, logically concat of A0 (row stride ksplit) and A1 (row stride
// K-ksplit) split at column ksplit. W bf16 [N,K] row-major. C f32. bias f32.
// Tile: BM=BN=128, BK=32. 256 threads = 4 waves (2x2), each wave 64x64 out
// (4x4 frags of 16x16x32 MFMA). Requires M%128==0, N%128==0, K%32==0,
// ksplit%32==0.
// ---------------------------------------------------------------------------
template <int ACT> // 0 = none, 1 = exact gelu
__global__ __launch_bounds__(256) void gemm_mfma(
    const __hip_bfloat16* __restrict__ A0, const __hip_bfloat16* __restrict__ A1,
    int ksplit, const __hip_bfloat16* __restrict__ W,
    const float* __restrict__ bias, float* __restrict__ C,
    int M, int N, int K)
{
    __shared__ __hip_bfloat16 As[128 * 32];  // [row][k] row-major, 8KB
    __shared__ __hip_bfloat16 Bs[128 * 32];  // [n][k]   row-major, 8KB

    const int n0 = blockIdx.x * 128;
    const int m0 = blockIdx.y * 128;
    const int tid = threadIdx.x;
    const int lane = tid & 63;
    const int w = tid >> 6;
    const int wy = w >> 1;   // wave m index (0..1)
    const int wx = w & 1;    // wave n index (0..1)

    // staging: 512 16B-chunks per 8KB tile; wave w covers chunks [w*64, w*64+64)
    // and [256+w*64, ...). LDS dest is wave-uniform base + lane*16 (HW rule).
    const int c0 = w * 64 + lane;
    const int c1 = c0 + 256;
    const int ar0 = c0 >> 2, ac0 = (c0 & 3) * 8;
    const int ar1 = c1 >> 2, ac1 = (c1 & 3) * 8;
    char* const ldsA0 = (char*)As + w * 1024;
    char* const ldsA1 = (char*)As + 4096 + w * 1024;
    char* const ldsB0 = (char*)Bs + w * 1024;
    char* const ldsB1 = (char*)Bs + 4096 + w * 1024;

    // fragment read bases (byte offsets into As/Bs), row stride 64B
    const char* const ardbase = (const char*)As + (wy * 64 + (lane & 15)) * 64 + (lane >> 4) * 16;
    const char* const brdbase = (const char*)Bs + (wx * 64 + (lane & 15)) * 64 + (lane >> 4) * 16;

    f32x4 acc[4][4] = {};

    for (int k0 = 0; k0 < K; k0 += 32) {
        const __hip_bfloat16* Ab;
        int as_, ko;
        if (k0 < ksplit) { Ab = A0; as_ = ksplit; ko = k0; }
        else             { Ab = A1; as_ = K - ksplit; ko = k0 - ksplit; }

        async_copy16(Ab + (size_t)(m0 + ar0) * as_ + ko + ac0, ldsA0);
        async_copy16(Ab + (size_t)(m0 + ar1) * as_ + ko + ac1, ldsA1);
        async_copy16(W + (size_t)(n0 + ar0) * K + k0 + ac0, ldsB0);
        async_copy16(W + (size_t)(n0 + ar1) * K + k0 + ac1, ldsB1);
        __syncthreads();   // drains vmcnt before barrier (compiler-inserted)

        s16x8 af[4], bfr[4];
        #pragma unroll
        for (int m = 0; m < 4; m++) af[m] = *(const s16x8*)(ardbase + m * 1024);
        #pragma unroll
        for (int n = 0; n < 4; n++) bfr[n] = *(const s16x8*)(brdbase + n * 1024);

        #pragma unroll
        for (int m = 0; m < 4; m++)
            #pragma unroll
            for (int n = 0; n < 4; n++)
                acc[m][n] = __builtin_amdgcn_mfma_f32_16x16x32_bf16(
                    af[m], bfr[n], acc[m][n], 0, 0, 0);
        __syncthreads();
    }

    // epilogue: C/D layout col=lane&15, row=(lane>>4)*4+reg  [m89]
    const int row_l = (lane >> 4) * 4;
    const int col_l = lane & 15;
    #pragma unroll
    for (int n = 0; n < 4; n++) {
        const int gcol = n0 + wx * 64 + n * 16 + col_l;
        const float bv = bias[gcol];
        #pragma unroll
        for (int m = 0; m < 4; m++) {
            const int grow0 = m0 + wy * 64 + m * 16 + row_l;
            #pragma unroll
            for (int r = 0; r < 4; r++) {
                float v = acc[m][n][r] + bv;
                if (ACT == 1) v = 0.5f * v * (1.0f + erff(v * 0.7071067811865475f));
                C[(size_t)(grow0 + r) * N + gcol] = v;
            }
        }
    }
}

// ---------------------------------------------------------------------------
// f32 -> bf16 cast, 8 elems/thread (n8 = n/8)
// ---------------------------------------------------------------------------
__global__ __launch_bounds__(256) void cast_bf16(
    const float* __restrict__ in, __hip_bfloat16* __restrict__ out, int n8)
{
    int i = blockIdx.x * 256 + threadIdx.x;
    const int stride = gridDim.x * 256;
    for (; i < n8; i += stride) {
        const float4 v0 = ((const float4*)in)[i * 2];
        const float4 v1 = ((const float4*)in)[i * 2 + 1];
        union { __hip_bfloat16 b[8]; s16x8 v; } o;
        o.b[0] = __float2bfloat16(v0.x); o.b[1] = __float2bfloat16(v0.y);
        o.b[2] = __float2bfloat16(v0.z); o.b[3] = __float2bfloat16(v0.w);
        o.b[4] = __float2bfloat16(v1.x); o.b[5] = __float2bfloat16(v1.y);
        o.b[6] = __float2bfloat16(v1.z); o.b[7] = __float2bfloat16(v1.w);
        ((s16x8*)out)[i] = o.v;
    }
}

// ---------------------------------------------------------------------------
// Tiled f32 GEMM (kept for fc1, N=64): C = A @ W^T + bias
// ---------------------------------------------------------------------------
template <int ACT>
__global__ __launch_bounds__(256) void gemm_nt(
    const float* __restrict__ A0, const float* __restrict__ A1, int ksplit,
    const float* __restrict__ W, const float* __restrict__ bias,
    float* __restrict__ C, int M, int N, int K)
{
    __shared__ float As[16][68];
    __shared__ float Bs[16][68];

    const int n0 = blockIdx.x * 64;
    const int m0 = blockIdx.y * 64;
    const int tid = threadIdx.x;
    const int tx = tid & 15;
    const int ty = tid >> 4;
    const int lm = tid >> 2;
    const int lk = (tid & 3) * 4;
    const int s1 = ksplit;
    const int s2 = K - ksplit;

    float acc[4][4] = {};

    for (int k0 = 0; k0 < K; k0 += 16) {
        const int arow = m0 + lm;
        const int acol = k0 + lk;
        float4 av;
        if (acol < s1) av = *(const float4*)(A0 + (size_t)arow * s1 + acol);
        else           av = *(const float4*)(A1 + (size_t)arow * s2 + (acol - s1));
        const float4 wv = *(const float4*)(W + (size_t)(n0 + lm) * K + acol);

        As[lk + 0][lm] = av.x; As[lk + 1][lm] = av.y;
        As[lk + 2][lm] = av.z; As[lk + 3][lm] = av.w;
        Bs[lk + 0][lm] = wv.x; Bs[lk + 1][lm] = wv.y;
        Bs[lk + 2][lm] = wv.z; Bs[lk + 3][lm] = wv.w;
        __syncthreads();

        #pragma unroll
        for (int kk = 0; kk < 16; kk++) {
            const float4 a4 = *(const float4*)&As[kk][ty * 4];
            const float4 b4 = *(const float4*)&Bs[kk][tx * 4];
            const float ar[4] = {a4.x, a4.y, a4.z, a4.w};
            const float br[4] = {b4.x, b4.y, b4.z, b4.w};
            #pragma unroll
            for (int i = 0; i < 4; i++)
                #pragma unroll
                for (int j = 0; j < 4; j++)
                    acc[i][j] = fmaf(ar[i], br[j], acc[i][j]);
        }
        __syncthreads();
    }

    #pragma unroll
    for (int i = 0; i < 4; i++) {
        const int r = m0 + ty * 4 + i;
        #pragma unroll
        for (int j = 0; j < 4; j++) {
            const int c = n0 + tx * 4 + j;
            float v = acc[i][j] + bias[c];
            if (ACT == 1) v = 0.5f * v * (1.0f + erff(v * 0.7071067811865475f));
            C[(size_t)r * N + c] = v;
        }
    }
}

// ---------------------------------------------------------------------------
// GRU recurrent matvec (one step i)
// ---------------------------------------------------------------------------
__global__ __launch_bounds__(256) void gru_matvec(
    const float* __restrict__ h, const float* __restrict__ Wh,
    const float* __restrict__ bh, const int* __restrict__ fa,
    float* __restrict__ gh, int i)
{
    __shared__ float As[16][33];
    __shared__ float Bs[16][68];

    const int n0 = blockIdx.x * 64;
    const int m0 = blockIdx.y * 32;
    const int tid = threadIdx.x;
    const int tx = tid & 15;
    const int ty = tid >> 4;

    const int lmA = tid >> 3;
    const int lkA = (tid & 7) * 2;
    const int bA = m0 + lmA;
    const float* hxp = nullptr;
    if (i > 0) {
        const int pi = fa[bA * S_ + i];
        hxp = h + ((size_t)(bA * S_ + pi)) * D_;
    }
    const int lnW = tid >> 2;
    const int lkW = (tid & 3) * 4;
    const float* wp = Wh + (size_t)(n0 + lnW) * D_;

    float acc[2][4] = {};

    for (int k0 = 0; k0 < D_; k0 += 16) {
        float2 av = make_float2(0.f, 0.f);
        if (i > 0) av = *(const float2*)(hxp + k0 + lkA);
        const float4 wv = *(const float4*)(wp + k0 + lkW);

        As[lkA + 0][lmA] = av.x;
        As[lkA + 1][lmA] = av.y;
        Bs[lkW + 0][lnW] = wv.x; Bs[lkW + 1][lnW] = wv.y;
        Bs[lkW + 2][lnW] = wv.z; Bs[lkW + 3][lnW] = wv.w;
        __syncthreads();

        #pragma unroll
        for (int kk = 0; kk < 16; kk++) {
            const float a0 = As[kk][ty];
            const float a1 = As[kk][ty + 16];
            const float4 b4 = *(const float4*)&Bs[kk][tx * 4];
            const float br[4] = {b4.x, b4.y, b4.z, b4.w};
            #pragma unroll
            for (int j = 0; j < 4; j++) {
                acc[0][j] = fmaf(a0, br[j], acc[0][j]);
                acc[1][j] = fmaf(a1, br[j], acc[1][j]);
            }
        }
        __syncthreads();
    }

    #pragma unroll
    for (int mi = 0; mi < 2; mi++) {
        const int bb = m0 + ty + mi * 16;
        #pragma unroll
        for (int j = 0; j < 4; j++) {
            const int e = n0 + tx * 4 + j;
            gh[(size_t)bb * E3_ + e] = acc[mi][j] + bh[e];
        }
    }
}

__device__ inline float2 blockReduce2(float s1, float s2, float* sm)
{
    #pragma unroll
    for (int off = 32; off > 0; off >>= 1) {
        s1 += __shfl_down(s1, off);
        s2 += __shfl_down(s2, off);
    }
    const int lane = threadIdx.x & 63;
    const int w = threadIdx.x >> 6;
    if (lane == 0) { sm[w] = s1; sm[w + 4] = s2; }
    __syncthreads();
    const float r1 = sm[0] + sm[1] + sm[2] + sm[3];
    const float r2 = sm[4] + sm[5] + sm[6] + sm[7];
    __syncthreads();
    return make_float2(r1, r2);
}

__device__ inline float sigmoidf_(float x) { return 1.0f / (1.0f + expf(-x)); }

// ---------------------------------------------------------------------------
// GRU gates (one step i)
// ---------------------------------------------------------------------------
__global__ __launch_bounds__(256) void gru_gates(
    const float* __restrict__ gx_all, const float* __restrict__ gh_all,
    const float* __restrict__ ln_g, const float* __restrict__ ln_b,
    const int* __restrict__ fa, float* __restrict__ h, int i)
{
    __shared__ float sm[8];
    const int b = blockIdx.x;
    const int tid = threadIdx.x;
    const int d0 = tid * 4;

    const float* gx = gx_all + (size_t)(b * S_ + i) * E3_;
    const float* gh = gh_all + (size_t)b * E3_;
    float* hout = h + (size_t)(b * S_ + i) * D_;

    float hx[4] = {0.f, 0.f, 0.f, 0.f};
    if (i > 0) {
        const int pi = fa[b * S_ + i];
        const float4 v = *(const float4*)(h + (size_t)(b * S_ + pi) * D_ + d0);
        hx[0] = v.x; hx[1] = v.y; hx[2] = v.z; hx[3] = v.w;
    }

    float u[4];
    {
        const float4 a = *(const float4*)(gx + d0);
        const float4 c = *(const float4*)(gh + d0);
        u[0] = a.x + c.x; u[1] = a.y + c.y; u[2] = a.z + c.z; u[3] = a.w + c.w;
    }
    float r[4];
    {
        float p1 = u[0] + u[1] + u[2] + u[3];
        float p2 = u[0]*u[0] + u[1]*u[1] + u[2]*u[2] + u[3]*u[3];
        const float2 t = blockReduce2(p1, p2, sm);
        const float mean = t.x * (1.0f / 1024.0f);
        const float var = t.y * (1.0f / 1024.0f) - mean * mean;
        const float rstd = rsqrtf(var + 1e-5f);
        const float4 g = *(const float4*)(ln_g + d0);
        const float4 be = *(const float4*)(ln_b + d0);
        const float gr[4] = {g.x, g.y, g.z, g.w};
        const float br[4] = {be.x, be.y, be.z, be.w};
        #pragma unroll
        for (int j = 0; j < 4; j++)
            r[j] = sigmoidf_((u[j] - mean) * rstd * gr[j] + br[j]);
    }

    {
        const float4 a = *(const float4*)(gx + D_ + d0);
        const float4 c = *(const float4*)(gh + D_ + d0);
        u[0] = a.x + c.x; u[1] = a.y + c.y; u[2] = a.z + c.z; u[3] = a.w + c.w;
    }
    float z[4];
    {
        float p1 = u[0] + u[1] + u[2] + u[3];
        float p2 = u[0]*u[0] + u[1]*u[1] + u[2]*u[2] + u[3]*u[3];
        const float2 t = blockReduce2(p1, p2, sm);
        const float mean = t.x * (1.0f / 1024.0f);
        const float var = t.y * (1.0f / 1024.0f) - mean * mean;
        const float rstd = rsqrtf(var + 1e-5f);
        const float4 g = *(const float4*)(ln_g + D_ + d0);
        const float4 be = *(const float4*)(ln_b + D_ + d0);
        const float gr[4] = {g.x, g.y, g.z, g.w};
        const float br[4] = {be.x, be.y, be.z, be.w};
        #pragma unroll
        for (int j = 0; j < 4; j++)
            z[j] = sigmoidf_((u[j] - mean) * rstd * gr[j] + br[j]);
    }

    {
        const float4 a = *(const float4*)(gx + 2 * D_ + d0);
        const float4 c = *(const float4*)(gh + 2 * D_ + d0);
        u[0] = a.x + r[0] * c.x; u[1] = a.y + r[1] * c.y;
        u[2] = a.z + r[2] * c.z; u[3] = a.w + r[3] * c.w;
    }
    float hn[4];
    {
        float p1 = u[0] + u[1] + u[2] + u[3];
        float p2 = u[0]*u[0] + u[1]*u[1] + u[2]*u[2] + u[3]*u[3];
        const float2 t = blockReduce2(p1, p2, sm);
        const float mean = t.x * (1.0f / 1024.0f);
        const float var = t.y * (1.0f / 1024.0f) - mean * mean;
        const float rstd = rsqrtf(var + 1e-5f);
        const float4 g = *(const float4*)(ln_g + 2 * D_ + d0);
        const float4 be = *(const float4*)(ln_b + 2 * D_ + d0);
        const float gr[4] = {g.x, g.y, g.z, g.w};
        const float br[4] = {be.x, be.y, be.z, be.w};
        #pragma unroll
        for (int j = 0; j < 4; j++) {
            const float n = tanhf((u[j] - mean) * rstd * gr[j] + br[j]);
            hn[j] = (1.0f - z[j]) * n + z[j] * hx[j];
        }
    }

    float4 o;
    o.x = hn[0]; o.y = hn[1]; o.z = hn[2]; o.w = hn[3];
    *(float4*)(hout + d0) = o;
}

// ---------------------------------------------------------------------------
// emb scan via ancestor chains; writes bf16 directly (feeds cmb MFMA GEMM)
// ---------------------------------------------------------------------------
__global__ __launch_bounds__(256) void emb_fill(
    const float* __restrict__ shorted, const int* __restrict__ fa,
    __hip_bfloat16* __restrict__ emb)
{
    __shared__ int src[16];
    const int bi = blockIdx.x;
    const int b = bi >> 7;
    const int i = bi & 127;
    if (threadIdx.x == 0) {
        int cur = i;
        bool dead = false;
        #pragma unroll
        for (int j = 0; j < 16; j++) {
            src[j] = dead ? -1 : cur;
            if (cur == 0) dead = true;
            cur = fa[(b << 7) + cur];
        }
    }
    __syncthreads();
    const int d = threadIdx.x * 4;
    const int j = d >> 6;
    const int s = src[j];
    float4 v = make_float4(0.f, 0.f, 0.f, 0.f);
    if (s >= 0)
        v = *(const float4*)(shorted + ((size_t)(b * S_ + s)) * DS_ + (d & 63));
    union { __hip_bfloat16 b4[4]; ushort4 u; } o;
    o.b4[0] = __float2bfloat16(v.x); o.b4[1] = __float2bfloat16(v.y);
    o.b4[2] = __float2bfloat16(v.z); o.b4[3] = __float2bfloat16(v.w);
    *(ushort4*)(emb + (size_t)bi * D_ + d) = o.u;
}

// ---------------------------------------------------------------------------
extern "C" void kernel_launch(void* const* d_in, const int* in_sizes, int n_in,
                              void* d_out, int out_size, void* d_ws, size_t ws_size,
                              hipStream_t stream)
{
    const float* token = (const float*)d_in[0];
    const float* Wx    = (const float*)d_in[1];
    const float* bx    = (const float*)d_in[2];
    const float* Wh    = (const float*)d_in[3];
    const float* bh    = (const float*)d_in[4];
    const float* ln_g  = (const float*)d_in[5];
    const float* ln_b  = (const float*)d_in[6];
    const float* fc0_w = (const float*)d_in[7];
    const float* fc0_b = (const float*)d_in[8];
    const float* fc1_w = (const float*)d_in[9];
    const float* fc1_b = (const float*)d_in[10];
    const float* cmb_w = (const float*)d_in[11];
    const float* cmb_b = (const float*)d_in[12];
    const int*   fa    = (const int*)d_in[13];

    float* out = (float*)d_out;
    char* ws = (char*)d_ws;

    const int M = B_ * S_;                       // 16384

    // ---- workspace layout (bytes) ----
    const size_t gx_off      = 0;                 // f32 [16384,3072] = 201326592
    const size_t gh_off      = 201326592;         // f32 [128,3072]   = 1572864
    const size_t shorted_off = 202899456;         // f32 [16384,64]   = 4194304
    const size_t wxbf_off    = 207093760;         // bf16 [3072,1024] = 6291456
    const size_t fc0wbf_off  = 213385216;         // bf16 [1024,1024] = 2097152
    const size_t cmbwbf_off  = 215482368;         // bf16 [1024,2048] = 4194304
    const size_t tokbf_off   = 219676672;         // bf16 [16384,1024]= 33554432
    // after scan, gx region is dead -> overlay:
    const size_t hbf_off     = 0;                 // bf16 [16384,1024]= 33554432
    const size_t h0_off      = 33554432;          // f32  [16384,1024]= 67108864
    const size_t embbf_off   = 100663296;         // bf16 [16384,1024]= 33554432

    float* gx            = (float*)(ws + gx_off);
    float* gh            = (float*)(ws + gh_off);
    float* shorted       = (float*)(ws + shorted_off);
    __hip_bfloat16* wxbf   = (__hip_bfloat16*)(ws + wxbf_off);
    __hip_bfloat16* fc0wbf = (__hip_bfloat16*)(ws + fc0wbf_off);
    __hip_bfloat16* cmbwbf = (__hip_bfloat16*)(ws + cmbwbf_off);
    __hip_bfloat16* tokbf  = (__hip_bfloat16*)(ws + tokbf_off);
    __hip_bfloat16* hbf    = (__hip_bfloat16*)(ws + hbf_off);
    float* h0            = (float*)(ws + h0_off);
    __hip_bfloat16* embbf  = (__hip_bfloat16*)(ws + embbf_off);
    float* h = out;  // gru_emb lives in d_out during the scan

    // ---- casts ----
    {
        int n8 = (M * D_) / 8;           // token: 2,097,152
        cast_bf16<<<2048, 256, 0, stream>>>(token, tokbf, n8);
        n8 = (E3_ * D_) / 8;
        cast_bf16<<<1536, 256, 0, stream>>>(Wx, wxbf, n8);
        n8 = (D_ * D_) / 8;
        cast_bf16<<<512, 256, 0, stream>>>(fc0_w, fc0wbf, n8);
        n8 = (D_ * 2 * D_) / 8;
        cast_bf16<<<1024, 256, 0, stream>>>(cmb_w, cmbwbf, n8);
    }

    // 1. gx = token @ Wx^T + bx   (bf16 MFMA)
    gemm_mfma<0><<<dim3(E3_ / 128, M / 128), 256, 0, stream>>>(
        tokbf, tokbf, D_, wxbf, bx, gx, M, E3_, D_);

    // 2. GRU scan (sequential, f32)
    for (int i = 0; i < S_; i++) {
        gru_matvec<<<dim3(E3_ / 64, B_ / 32), 256, 0, stream>>>(h, Wh, bh, fa, gh, i);
        gru_gates<<<B_, 256, 0, stream>>>(gx, gh, ln_g, ln_b, fa, h, i);
    }

    // 3. h -> bf16; h0 = gelu(h @ fc0_w^T + fc0_b)  (bf16 MFMA)
    cast_bf16<<<2048, 256, 0, stream>>>(h, hbf, (M * D_) / 8);
    gemm_mfma<1><<<dim3(D_ / 128, M / 128), 256, 0, stream>>>(
        hbf, hbf, D_, fc0wbf, fc0_b, h0, M, D_, D_);

    // 4. shorted = h0 @ fc1_w^T + fc1_b  (f32, N=64 small)
    gemm_nt<0><<<dim3(DS_ / 64, M / 64), 256, 0, stream>>>(
        h0, nullptr, D_, fc1_w, fc1_b, shorted, M, DS_, D_);

    // 5. emb via parallel ancestor-chain gather (writes bf16)
    emb_fill<<<M, 256, 0, stream>>>(shorted, fa, embbf);

    // 6. out = [token, emb] @ cmb_w^T + cmb_b  (bf16 MFMA, K split 1024+1024)
    gemm_mfma<0><<<dim3(D_ / 128, M / 128), 256, 0, stream>>>(
        tokbf, embbf, D_, cmbwbf, cmb_b, out, M, D_, 2 * D_);
}

// Round 3
// 3188.705 us; speedup vs baseline: 2.9725x; 2.1800x over previous
//
#include <hip/hip_runtime.h>
#include <hip/hip_bf16.h>
#include <math.h>

#define B_ 128
#define S_ 128
#define D_ 1024
#define DS_ 64
#define E3_ 3072   // 3*D

typedef short s16x8 __attribute__((ext_vector_type(8)));
typedef float f32x4 __attribute__((ext_vector_type(4)));

__device__ __forceinline__ void async_copy16(const void* g, void* l) {
    __builtin_amdgcn_global_load_lds(
        (const __attribute__((address_space(1))) void*)g,
        (__attribute__((address_space(3))) void*)l, 16, 0, 0);
}

// ---------------------------------------------------------------------------
// bf16 MFMA GEMM (m97 structure): C[M,N] = act( A[M,K] @ W[N,K]^T + bias[N] )
// A = concat(A0, A1) split at column ksplit. Tile BM=BN=128, BK=32.
// 256 threads = 4 waves (2x2), each wave 64x64 (4x4 frags of 16x16x32).
// OT: 0 = f32 out, 1 = bf16 out. ACT: 0 = none, 1 = exact gelu.
// ---------------------------------------------------------------------------
template <int ACT, int OT>
__global__ __launch_bounds__(256) void gemm_mfma(
    const __hip_bfloat16* __restrict__ A0, const __hip_bfloat16* __restrict__ A1,
    int ksplit, const __hip_bfloat16* __restrict__ W,
    const float* __restrict__ bias, void* __restrict__ Cv,
    int M, int N, int K)
{
    __shared__ __hip_bfloat16 As[128 * 32];  // 8KB
    __shared__ __hip_bfloat16 Bs[128 * 32];  // 8KB

    const int n0 = blockIdx.x * 128;
    const int m0 = blockIdx.y * 128;
    const int tid = threadIdx.x;
    const int lane = tid & 63;
    const int w = tid >> 6;
    const int wy = w >> 1;
    const int wx = w & 1;

    const int c0 = w * 64 + lane;
    const int c1 = c0 + 256;
    const int ar0 = c0 >> 2, ac0 = (c0 & 3) * 8;
    const int ar1 = c1 >> 2, ac1 = (c1 & 3) * 8;
    char* const ldsA0 = (char*)As + w * 1024;
    char* const ldsA1 = (char*)As + 4096 + w * 1024;
    char* const ldsB0 = (char*)Bs + w * 1024;
    char* const ldsB1 = (char*)Bs + 4096 + w * 1024;

    const char* const ardbase = (const char*)As + (wy * 64 + (lane & 15)) * 64 + (lane >> 4) * 16;
    const char* const brdbase = (const char*)Bs + (wx * 64 + (lane & 15)) * 64 + (lane >> 4) * 16;

    f32x4 acc[4][4] = {};

    for (int k0 = 0; k0 < K; k0 += 32) {
        const __hip_bfloat16* Ab;
        int as_, ko;
        if (k0 < ksplit) { Ab = A0; as_ = ksplit; ko = k0; }
        else             { Ab = A1; as_ = K - ksplit; ko = k0 - ksplit; }

        async_copy16(Ab + (size_t)(m0 + ar0) * as_ + ko + ac0, ldsA0);
        async_copy16(Ab + (size_t)(m0 + ar1) * as_ + ko + ac1, ldsA1);
        async_copy16(W + (size_t)(n0 + ar0) * K + k0 + ac0, ldsB0);
        async_copy16(W + (size_t)(n0 + ar1) * K + k0 + ac1, ldsB1);
        __syncthreads();

        s16x8 af[4], bfr[4];
        #pragma unroll
        for (int m = 0; m < 4; m++) af[m] = *(const s16x8*)(ardbase + m * 1024);
        #pragma unroll
        for (int n = 0; n < 4; n++) bfr[n] = *(const s16x8*)(brdbase + n * 1024);

        #pragma unroll
        for (int m = 0; m < 4; m++)
            #pragma unroll
            for (int n = 0; n < 4; n++)
                acc[m][n] = __builtin_amdgcn_mfma_f32_16x16x32_bf16(
                    af[m], bfr[n], acc[m][n], 0, 0, 0);
        __syncthreads();
    }

    const int row_l = (lane >> 4) * 4;
    const int col_l = lane & 15;
    #pragma unroll
    for (int n = 0; n < 4; n++) {
        const int gcol = n0 + wx * 64 + n * 16 + col_l;
        const float bv = bias[gcol];
        #pragma unroll
        for (int m = 0; m < 4; m++) {
            const int grow0 = m0 + wy * 64 + m * 16 + row_l;
            #pragma unroll
            for (int r = 0; r < 4; r++) {
                float v = acc[m][n][r] + bv;
                if (ACT == 1) v = 0.5f * v * (1.0f + erff(v * 0.7071067811865475f));
                if (OT == 0)
                    ((float*)Cv)[(size_t)(grow0 + r) * N + gcol] = v;
                else
                    ((__hip_bfloat16*)Cv)[(size_t)(grow0 + r) * N + gcol] = __float2bfloat16(v);
            }
        }
    }
}

// ---------------------------------------------------------------------------
// bf16 MFMA GEMM, BN=64 tile (K=1024 fixed): C[.,N-tile] = A @ W^T + bias.
// If fa != nullptr: M=128 (grid.y==1) and A row r is the gathered GRU state
// row  A + (r*128 + fa[r*128+step])*1024  (used for the recurrent matvec).
// If step==0 && fa: C = bias broadcast (zero initial state).
// Tile BM=128, BN=64, BK=32; 4 waves 2x2, each 64x32 (4x2 frags).
// ---------------------------------------------------------------------------
__global__ __launch_bounds__(256) void gemm_mfma64(
    const __hip_bfloat16* __restrict__ A, const int* __restrict__ fa, int step,
    const __hip_bfloat16* __restrict__ W, const float* __restrict__ bias,
    float* __restrict__ C, int N)
{
    __shared__ __hip_bfloat16 As[128 * 32];  // 8KB
    __shared__ __hip_bfloat16 Bs[64 * 32];   // 4KB

    const int n0 = blockIdx.x * 64;
    const int m0 = blockIdx.y * 128;
    const int tid = threadIdx.x;

    if (fa && step == 0) {
        for (int t = tid; t < 128 * 64; t += 256) {
            const int r = t >> 6, c = n0 + (t & 63);
            C[(size_t)r * N + c] = bias[c];
        }
        return;
    }

    const int lane = tid & 63;
    const int w = tid >> 6;
    const int wy = w >> 1;
    const int wx = w & 1;

    // A: 512 16B chunks; this thread's two: c0, c1. B: 256 chunks, one each.
    const int c0 = w * 64 + lane;
    const int c1 = c0 + 256;
    const int ar0 = c0 >> 2, ac0 = (c0 & 3) * 8;
    const int ar1 = c1 >> 2, ac1 = (c1 & 3) * 8;
    const int br = w * 16 + (lane >> 2), bc = (lane & 3) * 8;

    const __hip_bfloat16 *ap0, *ap1;
    if (fa) {
        ap0 = A + ((size_t)(ar0 << 7) + fa[(ar0 << 7) + step]) * 1024;
        ap1 = A + ((size_t)(ar1 << 7) + fa[(ar1 << 7) + step]) * 1024;
    } else {
        ap0 = A + (size_t)(m0 + ar0) * 1024;
        ap1 = A + (size_t)(m0 + ar1) * 1024;
    }
    const __hip_bfloat16* wp = W + (size_t)(n0 + br) * 1024;

    char* const ldsA0 = (char*)As + w * 1024;
    char* const ldsA1 = (char*)As + 4096 + w * 1024;
    char* const ldsB  = (char*)Bs + w * 1024;

    const char* const ardbase = (const char*)As + (wy * 64 + (lane & 15)) * 64 + (lane >> 4) * 16;
    const char* const brdbase = (const char*)Bs + (wx * 32 + (lane & 15)) * 64 + (lane >> 4) * 16;

    f32x4 acc[4][2] = {};

    for (int k0 = 0; k0 < 1024; k0 += 32) {
        async_copy16(ap0 + k0 + ac0, ldsA0);
        async_copy16(ap1 + k0 + ac1, ldsA1);
        async_copy16(wp + k0 + bc, ldsB);
        __syncthreads();

        s16x8 af[4], bfr[2];
        #pragma unroll
        for (int m = 0; m < 4; m++) af[m] = *(const s16x8*)(ardbase + m * 1024);
        #pragma unroll
        for (int n = 0; n < 2; n++) bfr[n] = *(const s16x8*)(brdbase + n * 1024);

        #pragma unroll
        for (int m = 0; m < 4; m++)
            #pragma unroll
            for (int n = 0; n < 2; n++)
                acc[m][n] = __builtin_amdgcn_mfma_f32_16x16x32_bf16(
                    af[m], bfr[n], acc[m][n], 0, 0, 0);
        __syncthreads();
    }

    const int row_l = (lane >> 4) * 4;
    const int col_l = lane & 15;
    #pragma unroll
    for (int n = 0; n < 2; n++) {
        const int gcol = n0 + wx * 32 + n * 16 + col_l;
        const float bv = bias[gcol];
        #pragma unroll
        for (int m = 0; m < 4; m++) {
            const int grow0 = m0 + wy * 64 + m * 16 + row_l;
            #pragma unroll
            for (int r = 0; r < 4; r++)
                C[(size_t)(grow0 + r) * N + gcol] = acc[m][n][r] + bv;
        }
    }
}

// ---------------------------------------------------------------------------
// f32 -> bf16 cast, 8 elems/thread
// ---------------------------------------------------------------------------
__global__ __launch_bounds__(256) void cast_bf16(
    const float* __restrict__ in, __hip_bfloat16* __restrict__ out, int n8)
{
    int i = blockIdx.x * 256 + threadIdx.x;
    const int stride = gridDim.x * 256;
    for (; i < n8; i += stride) {
        const float4 v0 = ((const float4*)in)[i * 2];
        const float4 v1 = ((const float4*)in)[i * 2 + 1];
        union { __hip_bfloat16 b[8]; s16x8 v; } o;
        o.b[0] = __float2bfloat16(v0.x); o.b[1] = __float2bfloat16(v0.y);
        o.b[2] = __float2bfloat16(v0.z); o.b[3] = __float2bfloat16(v0.w);
        o.b[4] = __float2bfloat16(v1.x); o.b[5] = __float2bfloat16(v1.y);
        o.b[6] = __float2bfloat16(v1.z); o.b[7] = __float2bfloat16(v1.w);
        ((s16x8*)out)[i] = o.v;
    }
}

// ---------------------------------------------------------------------------
__device__ inline float2 blockReduce2(float s1, float s2, float* sm)
{
    #pragma unroll
    for (int off = 32; off > 0; off >>= 1) {
        s1 += __shfl_down(s1, off);
        s2 += __shfl_down(s2, off);
    }
    const int lane = threadIdx.x & 63;
    const int w = threadIdx.x >> 6;
    if (lane == 0) { sm[w] = s1; sm[w + 4] = s2; }
    __syncthreads();
    const float r1 = sm[0] + sm[1] + sm[2] + sm[3];
    const float r2 = sm[4] + sm[5] + sm[6] + sm[7];
    __syncthreads();
    return make_float2(r1, r2);
}

__device__ inline float sigmoidf_(float x) { return 1.0f / (1.0f + expf(-x)); }

// ---------------------------------------------------------------------------
// GRU gates (one step i). Writes h (f32, exact recurrent state) AND hbf
// (bf16 mirror feeding the next step's MFMA matvec + fc0).
// ---------------------------------------------------------------------------
__global__ __launch_bounds__(256) void gru_gates(
    const float* __restrict__ gx_all, const float* __restrict__ gh_all,
    const float* __restrict__ ln_g, const float* __restrict__ ln_b,
    const int* __restrict__ fa, float* __restrict__ h,
    __hip_bfloat16* __restrict__ hbf, int i)
{
    __shared__ float sm[8];
    const int b = blockIdx.x;
    const int tid = threadIdx.x;
    const int d0 = tid * 4;

    const float* gx = gx_all + (size_t)(b * S_ + i) * E3_;
    const float* gh = gh_all + (size_t)b * E3_;

    float hx[4] = {0.f, 0.f, 0.f, 0.f};
    if (i > 0) {
        const int pi = fa[b * S_ + i];
        const float4 v = *(const float4*)(h + (size_t)(b * S_ + pi) * D_ + d0);
        hx[0] = v.x; hx[1] = v.y; hx[2] = v.z; hx[3] = v.w;
    }

    float u[4];
    {
        const float4 a = *(const float4*)(gx + d0);
        const float4 c = *(const float4*)(gh + d0);
        u[0] = a.x + c.x; u[1] = a.y + c.y; u[2] = a.z + c.z; u[3] = a.w + c.w;
    }
    float r[4];
    {
        float p1 = u[0] + u[1] + u[2] + u[3];
        float p2 = u[0]*u[0] + u[1]*u[1] + u[2]*u[2] + u[3]*u[3];
        const float2 t = blockReduce2(p1, p2, sm);
        const float mean = t.x * (1.0f / 1024.0f);
        const float var = t.y * (1.0f / 1024.0f) - mean * mean;
        const float rstd = rsqrtf(var + 1e-5f);
        const float4 g = *(const float4*)(ln_g + d0);
        const float4 be = *(const float4*)(ln_b + d0);
        const float gr[4] = {g.x, g.y, g.z, g.w};
        const float br[4] = {be.x, be.y, be.z, be.w};
        #pragma unroll
        for (int j = 0; j < 4; j++)
            r[j] = sigmoidf_((u[j] - mean) * rstd * gr[j] + br[j]);
    }

    {
        const float4 a = *(const float4*)(gx + D_ + d0);
        const float4 c = *(const float4*)(gh + D_ + d0);
        u[0] = a.x + c.x; u[1] = a.y + c.y; u[2] = a.z + c.z; u[3] = a.w + c.w;
    }
    float z[4];
    {
        float p1 = u[0] + u[1] + u[2] + u[3];
        float p2 = u[0]*u[0] + u[1]*u[1] + u[2]*u[2] + u[3]*u[3];
        const float2 t = blockReduce2(p1, p2, sm);
        const float mean = t.x * (1.0f / 1024.0f);
        const float var = t.y * (1.0f / 1024.0f) - mean * mean;
        const float rstd = rsqrtf(var + 1e-5f);
        const float4 g = *(const float4*)(ln_g + D_ + d0);
        const float4 be = *(const float4*)(ln_b + D_ + d0);
        const float gr[4] = {g.x, g.y, g.z, g.w};
        const float br[4] = {be.x, be.y, be.z, be.w};
        #pragma unroll
        for (int j = 0; j < 4; j++)
            z[j] = sigmoidf_((u[j] - mean) * rstd * gr[j] + br[j]);
    }

    {
        const float4 a = *(const float4*)(gx + 2 * D_ + d0);
        const float4 c = *(const float4*)(gh + 2 * D_ + d0);
        u[0] = a.x + r[0] * c.x; u[1] = a.y + r[1] * c.y;
        u[2] = a.z + r[2] * c.z; u[3] = a.w + r[3] * c.w;
    }
    float hn[4];
    {
        float p1 = u[0] + u[1] + u[2] + u[3];
        float p2 = u[0]*u[0] + u[1]*u[1] + u[2]*u[2] + u[3]*u[3];
        const float2 t = blockReduce2(p1, p2, sm);
        const float mean = t.x * (1.0f / 1024.0f);
        const float var = t.y * (1.0f / 1024.0f) - mean * mean;
        const float rstd = rsqrtf(var + 1e-5f);
        const float4 g = *(const float4*)(ln_g + 2 * D_ + d0);
        const float4 be = *(const float4*)(ln_b + 2 * D_ + d0);
        const float gr[4] = {g.x, g.y, g.z, g.w};
        const float br[4] = {be.x, be.y, be.z, be.w};
        #pragma unroll
        for (int j = 0; j < 4; j++) {
            const float n = tanhf((u[j] - mean) * rstd * gr[j] + br[j]);
            hn[j] = (1.0f - z[j]) * n + z[j] * hx[j];
        }
    }

    const size_t ro = (size_t)(b * S_ + i) * D_ + d0;
    float4 o;
    o.x = hn[0]; o.y = hn[1]; o.z = hn[2]; o.w = hn[3];
    *(float4*)(h + ro) = o;
    union { __hip_bfloat16 b4[4]; ushort4 u4; } ob;
    ob.b4[0] = __float2bfloat16(hn[0]); ob.b4[1] = __float2bfloat16(hn[1]);
    ob.b4[2] = __float2bfloat16(hn[2]); ob.b4[3] = __float2bfloat16(hn[3]);
    *(ushort4*)(hbf + ro) = ob.u4;
}

// ---------------------------------------------------------------------------
// emb scan via ancestor chains; writes bf16 (feeds cmb MFMA GEMM)
// ---------------------------------------------------------------------------
__global__ __launch_bounds__(256) void emb_fill(
    const float* __restrict__ shorted, const int* __restrict__ fa,
    __hip_bfloat16* __restrict__ emb)
{
    __shared__ int src[16];
    const int bi = blockIdx.x;
    const int b = bi >> 7;
    const int i = bi & 127;
    if (threadIdx.x == 0) {
        int cur = i;
        bool dead = false;
        #pragma unroll
        for (int j = 0; j < 16; j++) {
            src[j] = dead ? -1 : cur;
            if (cur == 0) dead = true;
            cur = fa[(b << 7) + cur];
        }
    }
    __syncthreads();
    const int d = threadIdx.x * 4;
    const int j = d >> 6;
    const int s = src[j];
    float4 v = make_float4(0.f, 0.f, 0.f, 0.f);
    if (s >= 0)
        v = *(const float4*)(shorted + ((size_t)(b * S_ + s)) * DS_ + (d & 63));
    union { __hip_bfloat16 b4[4]; ushort4 u; } o;
    o.b4[0] = __float2bfloat16(v.x); o.b4[1] = __float2bfloat16(v.y);
    o.b4[2] = __float2bfloat16(v.z); o.b4[3] = __float2bfloat16(v.w);
    *(ushort4*)(emb + (size_t)bi * D_ + d) = o.u;
}

// ---------------------------------------------------------------------------
extern "C" void kernel_launch(void* const* d_in, const int* in_sizes, int n_in,
                              void* d_out, int out_size, void* d_ws, size_t ws_size,
                              hipStream_t stream)
{
    const float* token = (const float*)d_in[0];
    const float* Wx    = (const float*)d_in[1];
    const float* bx    = (const float*)d_in[2];
    const float* Wh    = (const float*)d_in[3];
    const float* bh    = (const float*)d_in[4];
    const float* ln_g  = (const float*)d_in[5];
    const float* ln_b  = (const float*)d_in[6];
    const float* fc0_w = (const float*)d_in[7];
    const float* fc0_b = (const float*)d_in[8];
    const float* fc1_w = (const float*)d_in[9];
    const float* fc1_b = (const float*)d_in[10];
    const float* cmb_w = (const float*)d_in[11];
    const float* cmb_b = (const float*)d_in[12];
    const int*   fa    = (const int*)d_in[13];

    float* out = (float*)d_out;
    char* ws = (char*)d_ws;
    const int M = B_ * S_;   // 16384

    // ---- workspace layout (bytes); peak usage ~249 MB ----
    // Phase 1 (gx GEMM + scan):
    //   gx    f32 [16384,3072] @ 0          (201326592)
    //   gh    f32 [128,3072]   @ 201326592  (1572864)
    //   whbf  bf16[3072,1024]  @ 202899456  (6291456)
    //   hbf   bf16[16384,1024] @ 209190912  (33554432)  <- tokbf1 overlays here
    //                                                      pre-scan (dead after gx GEMM)
    //   wxbf  bf16[3072,1024]  @ 242745344  (6291456)   -> peak 249036800
    // Phase 2 (post-scan, gx region dead, overlays @ 0):
    //   h0bf   bf16[16384,1024] @ 0
    //   embbf  bf16[16384,1024] @ 33554432
    //   tokbf2 bf16[16384,1024] @ 67108864
    //   fc0wbf bf16[1024,1024]  @ 100663296
    //   cmbwbf bf16[1024,2048]  @ 102760448
    //   fc1wbf bf16[64,1024]    @ 106954752
    //   shorted f32[16384,64]   @ 107085824  (ends 111280128)
    float* gx              = (float*)(ws + 0);
    float* gh              = (float*)(ws + 201326592);
    __hip_bfloat16* whbf   = (__hip_bfloat16*)(ws + 202899456);
    __hip_bfloat16* hbf    = (__hip_bfloat16*)(ws + 209190912);
    __hip_bfloat16* tokbf1 = (__hip_bfloat16*)(ws + 209190912); // overlays hbf (pre-scan only)
    __hip_bfloat16* wxbf   = (__hip_bfloat16*)(ws + 242745344);

    __hip_bfloat16* h0bf   = (__hip_bfloat16*)(ws + 0);
    __hip_bfloat16* embbf  = (__hip_bfloat16*)(ws + 33554432);
    __hip_bfloat16* tokbf2 = (__hip_bfloat16*)(ws + 67108864);
    __hip_bfloat16* fc0wbf = (__hip_bfloat16*)(ws + 100663296);
    __hip_bfloat16* cmbwbf = (__hip_bfloat16*)(ws + 102760448);
    __hip_bfloat16* fc1wbf = (__hip_bfloat16*)(ws + 106954752);
    float* shorted         = (float*)(ws + 107085824);

    float* h = out;  // f32 recurrent state lives in d_out during the scan

    // ---- phase-1 casts ----
    cast_bf16<<<2048, 256, 0, stream>>>(token, tokbf1, (M * D_) / 8);
    cast_bf16<<<1536, 256, 0, stream>>>(Wx, wxbf, (E3_ * D_) / 8);
    cast_bf16<<<1536, 256, 0, stream>>>(Wh, whbf, (E3_ * D_) / 8);

    // 1. gx = token @ Wx^T + bx   (bf16 MFMA)
    gemm_mfma<0, 0><<<dim3(E3_ / 128, M / 128), 256, 0, stream>>>(
        tokbf1, tokbf1, D_, wxbf, bx, gx, M, E3_, D_);

    // 2. GRU scan: per step, MFMA gather-matvec (gh = h[fa] @ Wh^T + bh)
    //    then fused gates (writes h f32 + hbf bf16).
    for (int i = 0; i < S_; i++) {
        gemm_mfma64<<<dim3(E3_ / 64, 1), 256, 0, stream>>>(
            hbf, fa, i, whbf, bh, gh, E3_);
        gru_gates<<<B_, 256, 0, stream>>>(gx, gh, ln_g, ln_b, fa, h, hbf, i);
    }

    // ---- phase-2 casts (overlay dead gx region) ----
    cast_bf16<<<512, 256, 0, stream>>>(fc0_w, fc0wbf, (D_ * D_) / 8);
    cast_bf16<<<1024, 256, 0, stream>>>(cmb_w, cmbwbf, (D_ * 2 * D_) / 8);
    cast_bf16<<<32, 256, 0, stream>>>(fc1_w, fc1wbf, (DS_ * D_) / 8);
    cast_bf16<<<2048, 256, 0, stream>>>(token, tokbf2, (M * D_) / 8);

    // 3. h0 = gelu(h @ fc0_w^T + fc0_b)  (bf16 MFMA, bf16 out)
    gemm_mfma<1, 1><<<dim3(D_ / 128, M / 128), 256, 0, stream>>>(
        hbf, hbf, D_, fc0wbf, fc0_b, h0bf, M, D_, D_);

    // 4. shorted = h0 @ fc1_w^T + fc1_b  (bf16 MFMA, N=64)
    gemm_mfma64<<<dim3(1, M / 128), 256, 0, stream>>>(
        h0bf, nullptr, 0, fc1wbf, fc1_b, shorted, DS_);

    // 5. emb via parallel ancestor-chain gather
    emb_fill<<<M, 256, 0, stream>>>(shorted, fa, embbf);

    // 6. out = [token, emb] @ cmb_w^T + cmb_b  (bf16 MFMA, K split 1024+1024)
    gemm_mfma<0, 0><<<dim3(D_ / 128, M / 128), 256, 0, stream>>>(
        tokbf2, embbf, D_, cmbwbf, cmb_b, out, M, D_, 2 * D_);
}

// Round 4
// 1298.224 us; speedup vs baseline: 7.3010x; 2.4562x over previous
//
#include <hip/hip_runtime.h>
#include <hip/hip_bf16.h>
#include <math.h>

#define B_ 128
#define S_ 128
#define D_ 1024
#define DS_ 64
#define E3_ 3072   // 3*D
#define LMAX_ 34   // max GRU dependency depth handled (true depth ~13-20)

typedef short s16x8 __attribute__((ext_vector_type(8)));
typedef float f32x4 __attribute__((ext_vector_type(4)));

__device__ __forceinline__ void async_copy16(const void* g, void* l) {
    __builtin_amdgcn_global_load_lds(
        (const __attribute__((address_space(1))) void*)g,
        (__attribute__((address_space(3))) void*)l, 16, 0, 0);
}

__device__ __forceinline__ float bf2f(unsigned short v) {
    union { unsigned u; float f; } c; c.u = ((unsigned)v) << 16; return c.f;
}

// ---------------------------------------------------------------------------
// bf16 MFMA GEMM (m97 structure): C[M,N] = act( A[M,K] @ W[N,K]^T + bias[N] )
// A = concat(A0, A1) split at column ksplit. Tile BM=BN=128, BK=32.
// OT: 0 = f32 out, 1 = bf16 out. ACT: 0 = none, 1 = exact gelu.
// ---------------------------------------------------------------------------
template <int ACT, int OT>
__global__ __launch_bounds__(256) void gemm_mfma(
    const __hip_bfloat16* __restrict__ A0, const __hip_bfloat16* __restrict__ A1,
    int ksplit, const __hip_bfloat16* __restrict__ W,
    const float* __restrict__ bias, void* __restrict__ Cv,
    int M, int N, int K)
{
    __shared__ __hip_bfloat16 As[128 * 32];  // 8KB
    __shared__ __hip_bfloat16 Bs[128 * 32];  // 8KB

    const int n0 = blockIdx.x * 128;
    const int m0 = blockIdx.y * 128;
    const int tid = threadIdx.x;
    const int lane = tid & 63;
    const int w = tid >> 6;
    const int wy = w >> 1;
    const int wx = w & 1;

    const int c0 = w * 64 + lane;
    const int c1 = c0 + 256;
    const int ar0 = c0 >> 2, ac0 = (c0 & 3) * 8;
    const int ar1 = c1 >> 2, ac1 = (c1 & 3) * 8;
    char* const ldsA0 = (char*)As + w * 1024;
    char* const ldsA1 = (char*)As + 4096 + w * 1024;
    char* const ldsB0 = (char*)Bs + w * 1024;
    char* const ldsB1 = (char*)Bs + 4096 + w * 1024;

    const char* const ardbase = (const char*)As + (wy * 64 + (lane & 15)) * 64 + (lane >> 4) * 16;
    const char* const brdbase = (const char*)Bs + (wx * 64 + (lane & 15)) * 64 + (lane >> 4) * 16;

    f32x4 acc[4][4] = {};

    for (int k0 = 0; k0 < K; k0 += 32) {
        const __hip_bfloat16* Ab;
        int as_, ko;
        if (k0 < ksplit) { Ab = A0; as_ = ksplit; ko = k0; }
        else             { Ab = A1; as_ = K - ksplit; ko = k0 - ksplit; }

        async_copy16(Ab + (size_t)(m0 + ar0) * as_ + ko + ac0, ldsA0);
        async_copy16(Ab + (size_t)(m0 + ar1) * as_ + ko + ac1, ldsA1);
        async_copy16(W + (size_t)(n0 + ar0) * K + k0 + ac0, ldsB0);
        async_copy16(W + (size_t)(n0 + ar1) * K + k0 + ac1, ldsB1);
        __syncthreads();

        s16x8 af[4], bfr[4];
        #pragma unroll
        for (int m = 0; m < 4; m++) af[m] = *(const s16x8*)(ardbase + m * 1024);
        #pragma unroll
        for (int n = 0; n < 4; n++) bfr[n] = *(const s16x8*)(brdbase + n * 1024);

        #pragma unroll
        for (int m = 0; m < 4; m++)
            #pragma unroll
            for (int n = 0; n < 4; n++)
                acc[m][n] = __builtin_amdgcn_mfma_f32_16x16x32_bf16(
                    af[m], bfr[n], acc[m][n], 0, 0, 0);
        __syncthreads();
    }

    const int row_l = (lane >> 4) * 4;
    const int col_l = lane & 15;
    #pragma unroll
    for (int n = 0; n < 4; n++) {
        const int gcol = n0 + wx * 64 + n * 16 + col_l;
        const float bv = bias[gcol];
        #pragma unroll
        for (int m = 0; m < 4; m++) {
            const int grow0 = m0 + wy * 64 + m * 16 + row_l;
            #pragma unroll
            for (int r = 0; r < 4; r++) {
                float v = acc[m][n][r] + bv;
                if (ACT == 1) v = 0.5f * v * (1.0f + erff(v * 0.7071067811865475f));
                if (OT == 0)
                    ((float*)Cv)[(size_t)(grow0 + r) * N + gcol] = v;
                else
                    ((__hip_bfloat16*)Cv)[(size_t)(grow0 + r) * N + gcol] = __float2bfloat16(v);
            }
        }
    }
}

// ---------------------------------------------------------------------------
// bf16 MFMA GEMM, BN=64, K=1024 fixed (used for fc1). grid (N/64, M/128).
// ---------------------------------------------------------------------------
__global__ __launch_bounds__(256) void gemm_mfma64(
    const __hip_bfloat16* __restrict__ A, const __hip_bfloat16* __restrict__ W,
    const float* __restrict__ bias, float* __restrict__ C, int N)
{
    __shared__ __hip_bfloat16 As[128 * 32];  // 8KB
    __shared__ __hip_bfloat16 Bs[64 * 32];   // 4KB

    const int n0 = blockIdx.x * 64;
    const int m0 = blockIdx.y * 128;
    const int tid = threadIdx.x;
    const int lane = tid & 63;
    const int w = tid >> 6;
    const int wy = w >> 1;
    const int wx = w & 1;

    const int c0 = w * 64 + lane;
    const int c1 = c0 + 256;
    const int ar0 = c0 >> 2, ac0 = (c0 & 3) * 8;
    const int ar1 = c1 >> 2, ac1 = (c1 & 3) * 8;
    const int bc = (lane & 3) * 8;
    const int br = w * 16 + (lane >> 2);

    const __hip_bfloat16* ap0 = A + (size_t)(m0 + ar0) * 1024;
    const __hip_bfloat16* ap1 = A + (size_t)(m0 + ar1) * 1024;
    const __hip_bfloat16* wp = W + (size_t)(n0 + br) * 1024;

    char* const ldsA0 = (char*)As + w * 1024;
    char* const ldsA1 = (char*)As + 4096 + w * 1024;
    char* const ldsB  = (char*)Bs + w * 1024;

    const char* const ardbase = (const char*)As + (wy * 64 + (lane & 15)) * 64 + (lane >> 4) * 16;
    const char* const brdbase = (const char*)Bs + (wx * 32 + (lane & 15)) * 64 + (lane >> 4) * 16;

    f32x4 acc[4][2] = {};

    for (int k0 = 0; k0 < 1024; k0 += 32) {
        async_copy16(ap0 + k0 + ac0, ldsA0);
        async_copy16(ap1 + k0 + ac1, ldsA1);
        async_copy16(wp + k0 + bc, ldsB);
        __syncthreads();

        s16x8 af[4], bfr[2];
        #pragma unroll
        for (int m = 0; m < 4; m++) af[m] = *(const s16x8*)(ardbase + m * 1024);
        #pragma unroll
        for (int n = 0; n < 2; n++) bfr[n] = *(const s16x8*)(brdbase + n * 1024);

        #pragma unroll
        for (int m = 0; m < 4; m++)
            #pragma unroll
            for (int n = 0; n < 2; n++)
                acc[m][n] = __builtin_amdgcn_mfma_f32_16x16x32_bf16(
                    af[m], bfr[n], acc[m][n], 0, 0, 0);
        __syncthreads();
    }

    const int row_l = (lane >> 4) * 4;
    const int col_l = lane & 15;
    #pragma unroll
    for (int n = 0; n < 2; n++) {
        const int gcol = n0 + wx * 32 + n * 16 + col_l;
        const float bv = bias[gcol];
        #pragma unroll
        for (int m = 0; m < 4; m++) {
            const int grow0 = m0 + wy * 64 + m * 16 + row_l;
            #pragma unroll
            for (int r = 0; r < 4; r++)
                C[(size_t)(grow0 + r) * N + gcol] = acc[m][n][r] + bv;
        }
    }
}

// ---------------------------------------------------------------------------
// Build level schedule. level_b(0)=0; level_b(i)=level_b(fa_i)+1.
// Deterministic (no cross-thread atomics). One block, 128 threads (one per b).
// Outputs: node_list[16384] grouped by level, gsrc[node] = parent row or -1,
// lvl_cnt[LMAX_], lvl_off[LMAX_].
// ---------------------------------------------------------------------------
__global__ __launch_bounds__(128) void build_levels(
    const int* __restrict__ fa, int* __restrict__ node_list,
    int* __restrict__ gsrc, int* __restrict__ lvl_cnt, int* __restrict__ lvl_off)
{
    __shared__ unsigned char lev[128][128];        // [b][i]
    __shared__ unsigned short cnt[LMAX_][128];     // [lvl][b]
    __shared__ unsigned short sbase[LMAX_][128];   // running write pos per (lvl,b)
    __shared__ int off[LMAX_ + 1];
    const int b = threadIdx.x;

    for (int l = 0; l < LMAX_; l++) cnt[l][b] = 0;
    __syncthreads();

    const int* fab = fa + b * 128;
    for (int i = 0; i < 128; i++) {
        int l = 0;
        if (i > 0) l = lev[b][fab[i]] + 1;
        if (l >= LMAX_) l = LMAX_ - 1;   // never expected; validation guards
        lev[b][i] = (unsigned char)l;
        cnt[l][b]++;
    }
    __syncthreads();

    if (b == 0) {
        int acc = 0;
        for (int l = 0; l < LMAX_; l++) {
            off[l] = acc;
            int t = 0;
            for (int bb = 0; bb < 128; bb++) t += cnt[l][bb];
            lvl_cnt[l] = t;
            lvl_off[l] = acc;
            acc += t;
        }
        off[LMAX_] = acc;
    }
    __syncthreads();

    // per-level prefix over b (thread l handles level l)
    if (b < LMAX_) {
        int run = off[b];
        for (int bb = 0; bb < 128; bb++) {
            sbase[b][bb] = (unsigned short)run;
            run += cnt[b][bb];
        }
    }
    __syncthreads();

    for (int i = 0; i < 128; i++) {
        const int l = lev[b][i];
        const int pos = sbase[l][b]++;
        node_list[pos] = (b << 7) | i;
        gsrc[(b << 7) | i] = (i == 0) ? -1 : ((b << 7) | fab[i]);
    }
}

// ---------------------------------------------------------------------------
// Level matvec: for nodes at level L (L>=1):
//   gh = hbf[gsrc[node]] @ Wh^T + bh   (gathered bf16 MFMA GEMM)
// e < 2048 (r,z thirds):  gx[node][e] = bf16( f32(gx[node][e]) + gh[e] )
// e >= 2048 (n third):    ghn[node][e-2048] = gh[e]   (f32, kept separate)
// Tile BM=128 nodes, BN=64, BK=32. grid (48, GY), grid-stride over m-tiles.
// ---------------------------------------------------------------------------
__global__ __launch_bounds__(256) void lvl_matvec(
    const __hip_bfloat16* __restrict__ hbf, const __hip_bfloat16* __restrict__ Wh,
    const float* __restrict__ bh, __hip_bfloat16* __restrict__ gx,
    float* __restrict__ ghn, const int* __restrict__ node_list,
    const int* __restrict__ gsrc, const int* __restrict__ lvl_cnt,
    const int* __restrict__ lvl_off, int L)
{
    const int cnt = lvl_cnt[L];
    if (cnt == 0) return;
    const int off = lvl_off[L];
    const int n0 = blockIdx.x * 64;

    __shared__ int nd[128];
    __shared__ int sr[128];
    __shared__ __hip_bfloat16 As[128 * 32];  // 8KB
    __shared__ __hip_bfloat16 Bs[64 * 32];   // 4KB

    const int tid = threadIdx.x;
    const int lane = tid & 63;
    const int w = tid >> 6;
    const int wy = w >> 1;
    const int wx = w & 1;

    const int c0 = w * 64 + lane;
    const int c1 = c0 + 256;
    const int ar0 = c0 >> 2, ac0 = (c0 & 3) * 8;
    const int ar1 = c1 >> 2, ac1 = (c1 & 3) * 8;
    const int bc = (lane & 3) * 8;
    const int br = w * 16 + (lane >> 2);
    const __hip_bfloat16* wp = Wh + (size_t)(n0 + br) * 1024;

    char* const ldsA0 = (char*)As + w * 1024;
    char* const ldsA1 = (char*)As + 4096 + w * 1024;
    char* const ldsB  = (char*)Bs + w * 1024;
    const char* const ardbase = (const char*)As + (wy * 64 + (lane & 15)) * 64 + (lane >> 4) * 16;
    const char* const brdbase = (const char*)Bs + (wx * 32 + (lane & 15)) * 64 + (lane >> 4) * 16;

    const int row_l = (lane >> 4) * 4;
    const int col_l = lane & 15;
    const bool nthird = (n0 >= 2048);

    for (int mt = blockIdx.y; mt * 128 < cnt; mt += gridDim.y) {
        __syncthreads();   // protect nd/sr against previous iteration's readers
        if (tid < 128) {
            const int idx = mt * 128 + tid;
            if (idx < cnt) {
                const int node = node_list[off + idx];
                nd[tid] = node;
                sr[tid] = gsrc[node];   // >= 0 for all L >= 1 nodes
            } else {
                nd[tid] = -1;
                sr[tid] = 0;            // padding: any valid row
            }
        }
        __syncthreads();

        const __hip_bfloat16* ap0 = hbf + (size_t)sr[ar0] * 1024;
        const __hip_bfloat16* ap1 = hbf + (size_t)sr[ar1] * 1024;

        f32x4 acc[4][2] = {};

        for (int k0 = 0; k0 < 1024; k0 += 32) {
            async_copy16(ap0 + k0 + ac0, ldsA0);
            async_copy16(ap1 + k0 + ac1, ldsA1);
            async_copy16(wp + k0 + bc, ldsB);
            __syncthreads();

            s16x8 af[4], bfr[2];
            #pragma unroll
            for (int m = 0; m < 4; m++) af[m] = *(const s16x8*)(ardbase + m * 1024);
            #pragma unroll
            for (int n = 0; n < 2; n++) bfr[n] = *(const s16x8*)(brdbase + n * 1024);

            #pragma unroll
            for (int m = 0; m < 4; m++)
                #pragma unroll
                for (int n = 0; n < 2; n++)
                    acc[m][n] = __builtin_amdgcn_mfma_f32_16x16x32_bf16(
                        af[m], bfr[n], acc[m][n], 0, 0, 0);
            __syncthreads();
        }

        #pragma unroll
        for (int n = 0; n < 2; n++) {
            const int e = n0 + wx * 32 + n * 16 + col_l;
            const float bv = bh[e];
            #pragma unroll
            for (int m = 0; m < 4; m++) {
                const int lr0 = wy * 64 + m * 16 + row_l;
                #pragma unroll
                for (int r = 0; r < 4; r++) {
                    const int node = nd[lr0 + r];
                    if (node < 0) continue;
                    const float v = acc[m][n][r] + bv;
                    if (!nthird) {
                        __hip_bfloat16* p = gx + (size_t)node * E3_ + e;
                        *p = __float2bfloat16(bf2f(*(unsigned short*)p) + v);
                    } else {
                        ghn[(size_t)node * D_ + (e - 2048)] = v;
                    }
                }
            }
        }
    }
}

// ---------------------------------------------------------------------------
__device__ inline float2 blockReduce2(float s1, float s2, float* sm)
{
    #pragma unroll
    for (int offs = 32; offs > 0; offs >>= 1) {
        s1 += __shfl_down(s1, offs);
        s2 += __shfl_down(s2, offs);
    }
    const int lane = threadIdx.x & 63;
    const int w = threadIdx.x >> 6;
    if (lane == 0) { sm[w] = s1; sm[w + 4] = s2; }
    __syncthreads();
    const float r1 = sm[0] + sm[1] + sm[2] + sm[3];
    const float r2 = sm[4] + sm[5] + sm[6] + sm[7];
    __syncthreads();
    return make_float2(r1, r2);
}

__device__ inline float sigmoidf_(float x) { return 1.0f / (1.0f + expf(-x)); }

// ---------------------------------------------------------------------------
// Level gates: per node at level L, full GRU gate update.
// gx row (bf16) holds: [xr+hr, xz+hz] (for src>=0; matvec pre-added) and xn.
// For src<0 (i==0 nodes): gh = bh, hx = 0.
// Writes h (f32, exact state) + hbf (bf16 mirror). Grid-stride over nodes.
// ---------------------------------------------------------------------------
__global__ __launch_bounds__(256) void lvl_gates(
    const __hip_bfloat16* __restrict__ gx, const float* __restrict__ ghn,
    const float* __restrict__ ln_g, const float* __restrict__ ln_b,
    const float* __restrict__ bh,
    float* __restrict__ h, __hip_bfloat16* __restrict__ hbf,
    const int* __restrict__ node_list, const int* __restrict__ gsrc,
    const int* __restrict__ lvl_cnt, const int* __restrict__ lvl_off, int L)
{
    const int cnt = lvl_cnt[L];
    const int off = lvl_off[L];
    __shared__ float sm[8];
    const int tid = threadIdx.x;
    const int d0 = tid * 4;

    for (int idx = blockIdx.x; idx < cnt; idx += gridDim.x) {
        const int node = node_list[off + idx];
        const int src = gsrc[node];
        const unsigned short* gxr = (const unsigned short*)(gx + (size_t)node * E3_);

        float hx[4] = {0.f, 0.f, 0.f, 0.f};
        if (src >= 0) {
            const float4 v = *(const float4*)(h + (size_t)src * D_ + d0);
            hx[0] = v.x; hx[1] = v.y; hx[2] = v.z; hx[3] = v.w;
        }

        float u[4];
        {
            const ushort4 a = *(const ushort4*)(gxr + d0);
            u[0] = bf2f(a.x); u[1] = bf2f(a.y); u[2] = bf2f(a.z); u[3] = bf2f(a.w);
            if (src < 0) {
                const float4 c = *(const float4*)(bh + d0);
                u[0] += c.x; u[1] += c.y; u[2] += c.z; u[3] += c.w;
            }
        }
        float r[4];
        {
            float p1 = u[0] + u[1] + u[2] + u[3];
            float p2 = u[0]*u[0] + u[1]*u[1] + u[2]*u[2] + u[3]*u[3];
            const float2 t = blockReduce2(p1, p2, sm);
            const float mean = t.x * (1.0f / 1024.0f);
            const float var = t.y * (1.0f / 1024.0f) - mean * mean;
            const float rstd = rsqrtf(var + 1e-5f);
            const float4 g = *(const float4*)(ln_g + d0);
            const float4 be = *(const float4*)(ln_b + d0);
            const float gr[4] = {g.x, g.y, g.z, g.w};
            const float br[4] = {be.x, be.y, be.z, be.w};
            #pragma unroll
            for (int j = 0; j < 4; j++)
                r[j] = sigmoidf_((u[j] - mean) * rstd * gr[j] + br[j]);
        }

        {
            const ushort4 a = *(const ushort4*)(gxr + D_ + d0);
            u[0] = bf2f(a.x); u[1] = bf2f(a.y); u[2] = bf2f(a.z); u[3] = bf2f(a.w);
            if (src < 0) {
                const float4 c = *(const float4*)(bh + D_ + d0);
                u[0] += c.x; u[1] += c.y; u[2] += c.z; u[3] += c.w;
            }
        }
        float z[4];
        {
            float p1 = u[0] + u[1] + u[2] + u[3];
            float p2 = u[0]*u[0] + u[1]*u[1] + u[2]*u[2] + u[3]*u[3];
            const float2 t = blockReduce2(p1, p2, sm);
            const float mean = t.x * (1.0f / 1024.0f);
            const float var = t.y * (1.0f / 1024.0f) - mean * mean;
            const float rstd = rsqrtf(var + 1e-5f);
            const float4 g = *(const float4*)(ln_g + D_ + d0);
            const float4 be = *(const float4*)(ln_b + D_ + d0);
            const float gr[4] = {g.x, g.y, g.z, g.w};
            const float br[4] = {be.x, be.y, be.z, be.w};
            #pragma unroll
            for (int j = 0; j < 4; j++)
                z[j] = sigmoidf_((u[j] - mean) * rstd * gr[j] + br[j]);
        }

        {
            const ushort4 a = *(const ushort4*)(gxr + 2 * D_ + d0);
            float hn4[4];
            if (src < 0) {
                const float4 c = *(const float4*)(bh + 2 * D_ + d0);
                hn4[0] = c.x; hn4[1] = c.y; hn4[2] = c.z; hn4[3] = c.w;
            } else {
                const float4 c = *(const float4*)(ghn + (size_t)node * D_ + d0);
                hn4[0] = c.x; hn4[1] = c.y; hn4[2] = c.z; hn4[3] = c.w;
            }
            u[0] = bf2f(a.x) + r[0] * hn4[0]; u[1] = bf2f(a.y) + r[1] * hn4[1];
            u[2] = bf2f(a.z) + r[2] * hn4[2]; u[3] = bf2f(a.w) + r[3] * hn4[3];
        }
        float hn[4];
        {
            float p1 = u[0] + u[1] + u[2] + u[3];
            float p2 = u[0]*u[0] + u[1]*u[1] + u[2]*u[2] + u[3]*u[3];
            const float2 t = blockReduce2(p1, p2, sm);
            const float mean = t.x * (1.0f / 1024.0f);
            const float var = t.y * (1.0f / 1024.0f) - mean * mean;
            const float rstd = rsqrtf(var + 1e-5f);
            const float4 g = *(const float4*)(ln_g + 2 * D_ + d0);
            const float4 be = *(const float4*)(ln_b + 2 * D_ + d0);
            const float gr[4] = {g.x, g.y, g.z, g.w};
            const float br[4] = {be.x, be.y, be.z, be.w};
            #pragma unroll
            for (int j = 0; j < 4; j++) {
                const float n = tanhf((u[j] - mean) * rstd * gr[j] + br[j]);
                hn[j] = (1.0f - z[j]) * n + z[j] * hx[j];
            }
        }

        const size_t ro = (size_t)node * D_ + d0;
        float4 o;
        o.x = hn[0]; o.y = hn[1]; o.z = hn[2]; o.w = hn[3];
        *(float4*)(h + ro) = o;
        union { __hip_bfloat16 b4[4]; ushort4 u4; } ob;
        ob.b4[0] = __float2bfloat16(hn[0]); ob.b4[1] = __float2bfloat16(hn[1]);
        ob.b4[2] = __float2bfloat16(hn[2]); ob.b4[3] = __float2bfloat16(hn[3]);
        *(ushort4*)(hbf + ro) = ob.u4;
    }
}

// ---------------------------------------------------------------------------
// f32 -> bf16 cast, 8 elems/thread
// ---------------------------------------------------------------------------
__global__ __launch_bounds__(256) void cast_bf16(
    const float* __restrict__ in, __hip_bfloat16* __restrict__ out, int n8)
{
    int i = blockIdx.x * 256 + threadIdx.x;
    const int stride = gridDim.x * 256;
    for (; i < n8; i += stride) {
        const float4 v0 = ((const float4*)in)[i * 2];
        const float4 v1 = ((const float4*)in)[i * 2 + 1];
        union { __hip_bfloat16 b[8]; s16x8 v; } o;
        o.b[0] = __float2bfloat16(v0.x); o.b[1] = __float2bfloat16(v0.y);
        o.b[2] = __float2bfloat16(v0.z); o.b[3] = __float2bfloat16(v0.w);
        o.b[4] = __float2bfloat16(v1.x); o.b[5] = __float2bfloat16(v1.y);
        o.b[6] = __float2bfloat16(v1.z); o.b[7] = __float2bfloat16(v1.w);
        ((s16x8*)out)[i] = o.v;
    }
}

// ---------------------------------------------------------------------------
// emb scan via ancestor chains; writes bf16 (feeds cmb MFMA GEMM)
// ---------------------------------------------------------------------------
__global__ __launch_bounds__(256) void emb_fill(
    const float* __restrict__ shorted, const int* __restrict__ fa,
    __hip_bfloat16* __restrict__ emb)
{
    __shared__ int src[16];
    const int bi = blockIdx.x;
    const int b = bi >> 7;
    const int i = bi & 127;
    if (threadIdx.x == 0) {
        int cur = i;
        bool dead = false;
        #pragma unroll
        for (int j = 0; j < 16; j++) {
            src[j] = dead ? -1 : cur;
            if (cur == 0) dead = true;
            cur = fa[(b << 7) + cur];
        }
    }
    __syncthreads();
    const int d = threadIdx.x * 4;
    const int j = d >> 6;
    const int s = src[j];
    float4 v = make_float4(0.f, 0.f, 0.f, 0.f);
    if (s >= 0)
        v = *(const float4*)(shorted + ((size_t)(b * S_ + s)) * DS_ + (d & 63));
    union { __hip_bfloat16 b4[4]; ushort4 u; } o;
    o.b4[0] = __float2bfloat16(v.x); o.b4[1] = __float2bfloat16(v.y);
    o.b4[2] = __float2bfloat16(v.z); o.b4[3] = __float2bfloat16(v.w);
    *(ushort4*)(emb + (size_t)bi * D_ + d) = o.u;
}

// ---------------------------------------------------------------------------
extern "C" void kernel_launch(void* const* d_in, const int* in_sizes, int n_in,
                              void* d_out, int out_size, void* d_ws, size_t ws_size,
                              hipStream_t stream)
{
    const float* token = (const float*)d_in[0];
    const float* Wx    = (const float*)d_in[1];
    const float* bx    = (const float*)d_in[2];
    const float* Wh    = (const float*)d_in[3];
    const float* bh    = (const float*)d_in[4];
    const float* ln_g  = (const float*)d_in[5];
    const float* ln_b  = (const float*)d_in[6];
    const float* fc0_w = (const float*)d_in[7];
    const float* fc0_b = (const float*)d_in[8];
    const float* fc1_w = (const float*)d_in[9];
    const float* fc1_b = (const float*)d_in[10];
    const float* cmb_w = (const float*)d_in[11];
    const float* cmb_b = (const float*)d_in[12];
    const int*   fa    = (const int*)d_in[13];

    float* out = (float*)d_out;
    char* ws = (char*)d_ws;
    const int M = B_ * S_;   // 16384

    // ---- workspace layout (bytes); peak 247.6 MB (<= proven 249 MB) ----
    // gxbf  bf16[16384][3072] @ 0           (100663296)  dead after scan
    // ghn   f32 [16384][1024] @ 100663296   (67108864)   dead after scan
    // hbf   bf16[16384][1024] @ 167772160   (33554432)   alive thru fc0
    // tokbf bf16[16384][1024] @ 201326592   (33554432)   alive thru cmb
    // whbf  bf16[3072][1024]  @ 234881024   (6291456)
    // wxbf  bf16[3072][1024]  @ 241172480   (6291456)
    // meta                    @ 247463936   (~132KB)
    // Phase-2 overlays (inside dead gxbf region):
    //   h0bf@0, embbf@33554432, fc0wbf@67108864, cmbwbf@69206016,
    //   fc1wbf@73400320, shorted@73531392 (ends 77725696)
    __hip_bfloat16* gxbf   = (__hip_bfloat16*)(ws + 0);
    float*          ghn    = (float*)(ws + 100663296);
    __hip_bfloat16* hbf    = (__hip_bfloat16*)(ws + 167772160);
    __hip_bfloat16* tokbf  = (__hip_bfloat16*)(ws + 201326592);
    __hip_bfloat16* whbf   = (__hip_bfloat16*)(ws + 234881024);
    __hip_bfloat16* wxbf   = (__hip_bfloat16*)(ws + 241172480);
    int* node_list         = (int*)(ws + 247463936);
    int* gsrc              = (int*)(ws + 247529472);
    int* lvl_cnt           = (int*)(ws + 247595008);
    int* lvl_off           = (int*)(ws + 247595264);

    __hip_bfloat16* h0bf   = (__hip_bfloat16*)(ws + 0);
    __hip_bfloat16* embbf  = (__hip_bfloat16*)(ws + 33554432);
    __hip_bfloat16* fc0wbf = (__hip_bfloat16*)(ws + 67108864);
    __hip_bfloat16* cmbwbf = (__hip_bfloat16*)(ws + 69206016);
    __hip_bfloat16* fc1wbf = (__hip_bfloat16*)(ws + 73400320);
    float*          shorted= (float*)(ws + 73531392);

    float* h = out;  // f32 recurrent state lives in d_out during the scan

    // ---- casts + schedule ----
    cast_bf16<<<2048, 256, 0, stream>>>(token, tokbf, (M * D_) / 8);
    cast_bf16<<<1536, 256, 0, stream>>>(Wx, wxbf, (E3_ * D_) / 8);
    cast_bf16<<<1536, 256, 0, stream>>>(Wh, whbf, (E3_ * D_) / 8);
    build_levels<<<1, 128, 0, stream>>>(fa, node_list, gsrc, lvl_cnt, lvl_off);

    // 1. gx = token @ Wx^T + bx   (bf16 MFMA, bf16 out)
    gemm_mfma<0, 1><<<dim3(E3_ / 128, M / 128), 256, 0, stream>>>(
        tokbf, tokbf, D_, wxbf, bx, gxbf, M, E3_, D_);

    // 2. levelized GRU scan
    lvl_gates<<<256, 256, 0, stream>>>(gxbf, ghn, ln_g, ln_b, bh, h, hbf,
                                       node_list, gsrc, lvl_cnt, lvl_off, 0);
    for (int L = 1; L < LMAX_; L++) {
        lvl_matvec<<<dim3(E3_ / 64, 8), 256, 0, stream>>>(
            hbf, whbf, bh, gxbf, ghn, node_list, gsrc, lvl_cnt, lvl_off, L);
        lvl_gates<<<256, 256, 0, stream>>>(gxbf, ghn, ln_g, ln_b, bh, h, hbf,
                                           node_list, gsrc, lvl_cnt, lvl_off, L);
    }

    // ---- phase-2 casts (overlay dead gxbf region) ----
    cast_bf16<<<512, 256, 0, stream>>>(fc0_w, fc0wbf, (D_ * D_) / 8);
    cast_bf16<<<1024, 256, 0, stream>>>(cmb_w, cmbwbf, (D_ * 2 * D_) / 8);
    cast_bf16<<<32, 256, 0, stream>>>(fc1_w, fc1wbf, (DS_ * D_) / 8);

    // 3. h0 = gelu(h @ fc0_w^T + fc0_b)  (bf16 MFMA, bf16 out)
    gemm_mfma<1, 1><<<dim3(D_ / 128, M / 128), 256, 0, stream>>>(
        hbf, hbf, D_, fc0wbf, fc0_b, h0bf, M, D_, D_);

    // 4. shorted = h0 @ fc1_w^T + fc1_b  (bf16 MFMA, N=64)
    gemm_mfma64<<<dim3(1, M / 128), 256, 0, stream>>>(
        h0bf, fc1wbf, fc1_b, shorted, DS_);

    // 5. emb via parallel ancestor-chain gather
    emb_fill<<<M, 256, 0, stream>>>(shorted, fa, embbf);

    // 6. out = [token, emb] @ cmb_w^T + cmb_b  (bf16 MFMA, K split 1024+1024)
    gemm_mfma<0, 0><<<dim3(D_ / 128, M / 128), 256, 0, stream>>>(
        tokbf, embbf, D_, cmbwbf, cmb_b, out, M, D_, 2 * D_);
}